// Round 1
// baseline (241.960 us; speedup 1.0000x reference)
//
#include <hip/hip_runtime.h>

#define BATCH 128
#define NPTS  4096
#define TPB   1024            // 4 elements per thread
#define EPT   4

// r = DT/DX = (0.75*DX/1.5)/DX = 0.5 exactly (all factors exact in fp64)
#define RCOEF 0.5f

// f(u)  = 1.5u + 0.75b u^2 + (-0.5-2b) u^3 + 1.5b u^4 - 0.25b u^6,  b = beta/12
// f'(u) = 1.5 + 1.5b u - (1.5+6b) u^2 + 6b u^3 - 1.5b u^5
__device__ __forceinline__ void flux_eval(float u, float& f, float& a) {
    constexpr float b  = 0.1f / 12.0f;
    constexpr float c6 = -0.25f * b;
    constexpr float c4 =  1.5f  * b;
    constexpr float c3 = -0.5f - 2.0f * b;
    constexpr float c2 =  0.75f * b;
    constexpr float c1 =  1.5f;
    constexpr float d5 = -1.5f * b;
    constexpr float d3 =  6.0f * b;
    constexpr float d2 = -(1.5f + 6.0f * b);
    constexpr float d1 =  1.5f * b;
    constexpr float d0 =  1.5f;

    // f/u Horner (deg-5 inner poly, c5 term == 0)
    float t = c6 * u;
    t = fmaf(t, u, c4);
    t = fmaf(t, u, c3);
    t = fmaf(t, u, c2);
    t = fmaf(t, u, c1);
    f = u * t;

    // f' Horner (deg-5, d4 term == 0)
    float d = d5 * u;
    d = d * u;            // (d5*u + d4)*u with d4 = 0 -> d5*u^2
    d = fmaf(d, u, d2);   // NOTE: see below — careful with d3
    // ^ wrong order placeholder, fixed in real sequence:
    a = d; // overwritten below
    float e = d5 * u;         // d5*u + d4 (d4==0)
    e = fmaf(e, u, d3);
    e = fmaf(e, u, d2);
    e = fmaf(e, u, d1);
    e = fmaf(e, u, d0);
    a = fabsf(e);
}

__global__ __launch_bounds__(TPB) void pde_rows_kernel(
        const float* __restrict__ init,
        const int*   __restrict__ stepnum_p,
        float*       __restrict__ out) {
    __shared__ __align__(16) float su[2][NPTS];

    const int b   = blockIdx.x;
    const int tid = threadIdx.x;
    const int i0  = tid << 2;                 // first owned element
    const int stepnum = *stepnum_p;

    // shifted halo-read indices (clamped; edge garbage feeds only the
    // boundary-copied outputs, which get overwritten)
    const int il = (i0 == 0)           ? 0  : i0 - EPT;
    const int ir = (i0 == NPTS - EPT)  ? i0 : i0 + EPT;

    // load init row -> LDS buf 0, and emit out[step=0] = init
    float4 v0 = *(const float4*)(init + (size_t)b * NPTS + i0);
    *(float4*)(&su[0][i0]) = v0;
    *(float4*)(out + (size_t)b * NPTS + i0) = v0;
    __syncthreads();

    int cur = 0;
    for (int s = 1; s < stepnum; ++s) {
        const float* U = su[cur];

        const float4 lm = *(const float4*)(U + il);
        const float4 mm = *(const float4*)(U + i0);
        const float4 rm = *(const float4*)(U + ir);

        float v[6] = { lm.w, mm.x, mm.y, mm.z, mm.w, rm.x };

        float f[6], a[6];
#pragma unroll
        for (int k = 0; k < 6; ++k) flux_eval(v[k], f[k], a[k]);

        float fh[5];
#pragma unroll
        for (int m = 0; m < 5; ++m) {
            const float am = fmaxf(a[m], a[m + 1]);
            fh[m] = 0.5f * (f[m] + f[m + 1]) - 0.5f * am * (v[m + 1] - v[m]);
        }

        float un[EPT];
#pragma unroll
        for (int t = 0; t < EPT; ++t)
            un[t] = fmaf(-RCOEF, fh[t + 1] - fh[t], v[t + 1]);

        // boundary copy: u_new[0] = u_new[1], u_new[N-1] = u_new[N-2]
        if (tid == 0)       un[0] = un[1];
        if (tid == TPB - 1) un[3] = un[2];

        const float4 w = make_float4(un[0], un[1], un[2], un[3]);
        *(float4*)(&su[cur ^ 1][i0]) = w;
        *(float4*)(out + (size_t)s * (BATCH * NPTS) + (size_t)b * NPTS + i0) = w;

        cur ^= 1;
        __syncthreads();
    }
}

extern "C" void kernel_launch(void* const* d_in, const int* in_sizes, int n_in,
                              void* d_out, int out_size, void* d_ws, size_t ws_size,
                              hipStream_t stream) {
    const float* init  = (const float*)d_in[0];
    const int*   steps = (const int*)d_in[1];
    float*       out   = (float*)d_out;
    pde_rows_kernel<<<BATCH, TPB, 0, stream>>>(init, steps, out);
}

// Round 2
// 216.969 us; speedup vs baseline: 1.1152x; 1.1152x over previous
//
#include <hip/hip_runtime.h>

#define BATCH 128
#define NPTS  4096
#define HALF  2048
#define TPB   576                 // 9 waves
#define EPT   4
#define CWID  (TPB * EPT)         // 2304-cell compute region per block
#define HALO  (CWID - HALF)       // 256 >= 99 steps of contamination + margin

// Halved-coefficient flux: g(u) = 0.5*f(u), ah(u) = 0.5*|f'(u)|
// f  = 1.5u + 0.75b u^2 + (-0.5-2b) u^3 + 1.5b u^4 - 0.25b u^6,  b = beta/12
// f' = 1.5 + 1.5b u - (1.5+6b) u^2 + 6b u^3 - 1.5b u^5
__device__ __forceinline__ void flux_eval(float u, float& g, float& ah) {
    constexpr float b  = 0.1f / 12.0f;
    constexpr float c6 = 0.5f * (-0.25f * b);
    constexpr float c4 = 0.5f * ( 1.5f  * b);
    constexpr float c3 = 0.5f * (-0.5f - 2.0f * b);
    constexpr float c2 = 0.5f * ( 0.75f * b);
    constexpr float c1 = 0.5f * ( 1.5f);
    constexpr float d5 = 0.5f * (-1.5f * b);
    constexpr float d3 = 0.5f * ( 6.0f * b);
    constexpr float d2 = 0.5f * (-(1.5f + 6.0f * b));
    constexpr float d1 = 0.5f * ( 1.5f * b);
    constexpr float d0 = 0.5f * ( 1.5f);

    float t = c6 * u;            // c5 == 0
    t = fmaf(t, u, c4);
    t = fmaf(t, u, c3);
    t = fmaf(t, u, c2);
    t = fmaf(t, u, c1);
    g = u * t;

    float e = d5 * u;            // d4 == 0
    e = fmaf(e, u, d3);
    e = fmaf(e, u, d2);
    e = fmaf(e, u, d1);
    e = fmaf(e, u, d0);
    ah = fabsf(e);
}

__global__ __launch_bounds__(TPB) void pde_rows_split(
        const float* __restrict__ init,
        const int*   __restrict__ stepnum_p,
        float*       __restrict__ out) {
    // double-buffered per-thread edge exchange: (.x = leftmost owned, .y = rightmost owned)
    __shared__ __align__(8) float2 edge[2][TPB];

    const int blk  = blockIdx.x;
    const int row  = blk >> 1;
    const int half = blk & 1;
    const int tid  = threadIdx.x;
    const int base = half ? (NPTS - CWID) : 0;          // 1792 or 0
    const int g0   = base + (tid << 2);                 // first cell this thread computes
    const int stepnum = *stepnum_p;

    // store only owned (uncontaminated) cells; mask is wave-uniform:
    // half==0: tid<512 (cells 0..2047); half==1: tid>=64 (cells 2048..4095)
    const bool ownstore = half ? (tid >= (HALO >> 2)) : (tid < (HALF >> 2));
    const bool rowL = (half == 0) && (tid == 0);
    const bool rowR = (half == 1) && (tid == TPB - 1);
    const int  tl = (tid == 0) ? 0 : tid - 1;           // clamped: garbage feeds only
    const int  tr = (tid == TPB - 1) ? tid : tid + 1;   // contaminated/overwritten cells

    float4 v4 = *(const float4*)(init + (size_t)row * NPTS + g0);
    float v0 = v4.x, v1 = v4.y, v2 = v4.z, v3 = v4.w;

    if (ownstore)   // out[step=0] = init (reference applies no boundary copy at s=0)
        *(float4*)(out + (size_t)row * NPTS + g0) = v4;

    int buf = 0;
    for (int s = 1; s < stepnum; ++s) {
        edge[buf][tid] = make_float2(v0, v3);
        // LDS-visibility-only barrier: do NOT drain vmcnt — global stores of the
        // previous step keep retiring in the background (nothing ever reads them).
        asm volatile("s_waitcnt lgkmcnt(0)\n\ts_barrier" ::: "memory");
        const float vl = edge[buf][tl].y;
        const float vr = edge[buf][tr].x;
        buf ^= 1;

        float g[6], a[6];
        flux_eval(vl, g[0], a[0]);
        flux_eval(v0, g[1], a[1]);
        flux_eval(v1, g[2], a[2]);
        flux_eval(v2, g[3], a[3]);
        flux_eval(v3, g[4], a[4]);
        flux_eval(vr, g[5], a[5]);

        const float vv[6] = { vl, v0, v1, v2, v3, vr };
        float fh[5];
#pragma unroll
        for (int m = 0; m < 5; ++m)
            fh[m] = g[m] + g[m + 1] - fmaxf(a[m], a[m + 1]) * (vv[m + 1] - vv[m]);

        float u0 = fmaf(-0.5f, fh[1] - fh[0], v0);   // r = DT/DX = 0.5 exactly
        float u1 = fmaf(-0.5f, fh[2] - fh[1], v1);
        float u2 = fmaf(-0.5f, fh[3] - fh[2], v2);
        float u3 = fmaf(-0.5f, fh[4] - fh[3], v3);
        if (rowL) u0 = u1;                            // u_new[0]   = u_new[1]
        if (rowR) u3 = u2;                            // u_new[N-1] = u_new[N-2]
        v0 = u0; v1 = u1; v2 = u2; v3 = u3;

        if (ownstore)
            *(float4*)(out + (size_t)s * ((size_t)BATCH * NPTS)
                           + (size_t)row * NPTS + g0)
                = make_float4(v0, v1, v2, v3);
    }
}

extern "C" void kernel_launch(void* const* d_in, const int* in_sizes, int n_in,
                              void* d_out, int out_size, void* d_ws, size_t ws_size,
                              hipStream_t stream) {
    const float* init  = (const float*)d_in[0];
    const int*   steps = (const int*)d_in[1];
    float*       out   = (float*)d_out;
    pde_rows_split<<<BATCH * 2, TPB, 0, stream>>>(init, steps, out);
}